// Round 11
// baseline (28.994 us; speedup 1.0000x reference)
//
#include <hip/hip_runtime.h>

// Problem constants (fixed by setup_inputs):
//   x: (64,1,8,8) f32 = 16 KB TOTAL; KH=KW=5 -> oh=ow=4
//   rows n = b*16 + s, s = oy*4+ox, N = 1024; feat[n,k] = x[b*64+(oy+i)*8+(ox+j)], k=i*5+j
//   idx0:(128,36,6) in [0,25), lut0:(128,36,64)
//   idx1:(128, 6,6) in [0,36), lut1:(128, 6,64)
//   idx2:(128, 1,6) in [0, 6), lut2:(128, 1,64)
//   out[b,t,oy,ox] = b*2048 + t*16 + s
#define T_TREES 128
#define M0 36
#define M1 6
#define NNODES 43
#define NROWS 1024
#define XPAD 67   // odd LDS image stride -> gather banks sweep residues (~2-way max)
#define SLUT_ELEMS (T_TREES * NNODES * 64)   // 352256 floats = 1.41 MB

typedef float v2f __attribute__((ext_vector_type(2)));

__device__ __forceinline__ float sigmoidf(float v) {
    return 1.f / (1.f + __expf(-v));
}

// ---------------- pre-pass: slut[t][node][64] = sigmoid(lut) ----------------
// Required so the main kernels can s_load P straight into SGPRs (s_load only
// works from global memory; LDS staging would force P back through VGPRs).
__global__ __launch_bounds__(256) void sig_kernel(
    const float* __restrict__ lut0, const float* __restrict__ lut1,
    const float* __restrict__ lut2, float* __restrict__ slut) {
    int i4 = blockIdx.x * 256 + threadIdx.x;   // 88064 float4s, grid covers exactly
    int j4 = i4 & 15;          // float4 index within node (16 per node)
    int tn = i4 >> 4;          // t*43 + node
    int t = tn / NNODES;
    int node = tn - t * NNODES;
    const float4* src;
    if (node < M0)            src = (const float4*)lut0 + (t * M0 + node) * 16 + j4;
    else if (node < M0 + M1)  src = (const float4*)lut1 + (t * M1 + (node - M0)) * 16 + j4;
    else                      src = (const float4*)lut2 + t * 16 + j4;
    float4 v = *src;
    float4 r;
    r.x = sigmoidf(v.x); r.y = sigmoidf(v.y);
    r.z = sigmoidf(v.z); r.w = sigmoidf(v.w);
    reinterpret_cast<float4*>(slut)[i4] = r;
}

// Pair-weight, FMA-lean: {(1-a)(1-b),(1-a)b,a(1-b),ab} per 2-row lane.
__device__ __forceinline__ void pair_w(v2f a, v2f b, v2f w[4]) {
    v2f ab = a * b;
    w[3] = ab;
    w[2] = a - ab;
    w[1] = b - ab;
    w[0] = (1.f - a) - w[1];
}

// Trilinear contraction over a row-pair. P[] is compile-time-indexed; when it
// holds s_load results the FMAs read SGPR + VGPR operands (zero VGPR cost).
__device__ __forceinline__ v2f lut_node_v2(const float* __restrict__ P,
                                           v2f a, v2f b, v2f c,
                                           v2f d, v2f e, v2f f) {
    v2f wa[4], wb[4], wc[4];
    pair_w(a, b, wa);
    pair_w(c, d, wb);
    pair_w(e, f, wc);
    v2f acc = {0.f, 0.f};
#pragma unroll
    for (int p = 0; p < 4; ++p) {
        v2f tp = {0.f, 0.f};
#pragma unroll
        for (int q = 0; q < 4; ++q) {
            const float* Pq = P + p * 16 + q * 4;
            v2f tq = Pq[0] * wc[0] + Pq[1] * wc[1] + Pq[2] * wc[2] + Pq[3] * wc[3];
            tp += tq * wb[q];
        }
        acc += tp * wa[p];
    }
    return acc;
}

// ===== layer 0: wave-stationary node, row-pair per lane, P via s_load =====
// Wave w owns node (t, mg*4+w) for all 1024 rows (8 pair-iters). The node
// pointer is wave-uniform (blockIdx + readfirstlane) so P[i]=sl[i] compiles
// to s_load_dwordx16 -> SGPR-resident P. VGPR = working set only (~80-110)
// -> 16 waves/CU resident (vs 8 with P-in-VGPR: the 2-waves/SIMD cap that
// held every prior round at ~30% issue efficiency).
__global__ __launch_bounds__(256) void l0_kernel(
    const float* __restrict__ x, const int* __restrict__ idx0,
    const float* __restrict__ slut, float* __restrict__ h0) {
    __shared__ float xs[64 * XPAD];          // 17152 B -> 9 blocks/CU (not limiting)

    const int tid = threadIdx.x;
    const int bx = blockIdx.x;               // bx = mg*128 + t (t fast -> XCD locality)
    const int t = bx & 127;
    const int mg = bx >> 7;                  // node group [0,9)

    // stage x (coalesced float4 reads; scalar LDS writes, odd stride)
#pragma unroll
    for (int k = 0; k < 4; ++k) {
        int i4 = tid + k * 256;              // float4 index (16 per image)
        float4 v = reinterpret_cast<const float4*>(x)[i4];
        float* dst = xs + (i4 >> 4) * XPAD + (i4 & 15) * 4;
        dst[0] = v.x; dst[1] = v.y; dst[2] = v.z; dst[3] = v.w;
    }
    __syncthreads();

    const int wu = __builtin_amdgcn_readfirstlane(tid >> 6);  // uniform wave id
    const int ln = tid & 63;
    const int m = mg * 4 + wu;

    // P: 64 scalar loads from a uniform address -> s_load -> SGPRs
    const float* __restrict__ sl = slut + (t * NNODES + m) * 64;
    float P[64];
#pragma unroll
    for (int i = 0; i < 64; ++i) P[i] = sl[i];

    const int* id = idx0 + (t * M0 + m) * 6; // uniform -> s_load
    int di[6];
#pragma unroll
    for (int j = 0; j < 6; ++j) {
        int k = id[j];
        int ii = (k * 13) >> 6;              // k/5 for k in [0,25)
        di[j] = k - 5 * ii + ii * 8;         // i*8 + j window offset
    }

    float* __restrict__ hout = h0 + (t * M0 + m) * NROWS;
#pragma unroll 4
    for (int u = 0; u < 8; ++u) {
        int p = u * 64 + ln;                 // pair id: rows 2p,2p+1
        int b = p >> 3;                      // image
        int s = (p & 7) * 2;                 // even position
        int xb = b * XPAD + (s >> 2) * 8 + (s & 3);
        v2f g[6];
#pragma unroll
        for (int j = 0; j < 6; ++j) {
            int a0 = xb + di[j];
            g[j].x = xs[a0];                 // fuses -> ds_read2_b32
            g[j].y = xs[a0 + 1];
        }
        v2f r = lut_node_v2(P, g[0], g[1], g[2], g[3], g[4], g[5]);
        *reinterpret_cast<v2f*>(hout + 2 * p) = r;   // global_store_dwordx2
    }
}

// ===== layers 1+2: block = (t, eighth of rows), 1024 blocks x 384 thr =====
// No LDS LUT staging at all: wave w s_loads its node's P. 4 blocks/CU x 6
// waves = 24 waves/CU. h0 reads are coalesced v2f, XCD-local (writer blocks
// mg*128+t and reader blocks e*128+t agree mod 8 -> same L2).
__global__ __launch_bounds__(384) void l12_kernel(
    const float* __restrict__ h0, const int* __restrict__ idx1,
    const int* __restrict__ idx2, const float* __restrict__ slut,
    float* __restrict__ out) {
    __shared__ __align__(8) float h1s[M1 * 128];   // 3 KB

    const int tid = threadIdx.x;
    const int bx = blockIdx.x;               // bx = e*128 + t
    const int t = bx & 127;
    const int e = bx >> 7;                   // row eighth [0,8)

    const int wu = __builtin_amdgcn_readfirstlane(tid >> 6);  // 0..5
    const int ln = tid & 63;

    // layer 1: wave wu = node wu of tree t over rows [e*128, e*128+128)
    {
        const float* __restrict__ sl = slut + (t * NNODES + M0 + wu) * 64;
        float P[64];
#pragma unroll
        for (int i = 0; i < 64; ++i) P[i] = sl[i];
        const int* id = idx1 + (t * M1 + wu) * 6;   // uniform -> s_load
        int rr = e * 128 + 2 * ln;                  // global even row
        v2f g[6];
#pragma unroll
        for (int j = 0; j < 6; ++j)
            g[j] = *reinterpret_cast<const v2f*>(h0 + (t * M0 + id[j]) * NROWS + rr);
        v2f r = lut_node_v2(P, g[0], g[1], g[2], g[3], g[4], g[5]);
        *reinterpret_cast<v2f*>(h1s + wu * 128 + 2 * ln) = r;
    }
    __syncthreads();

    // layer 2: wave 0, one pair per lane
    if (tid < 64) {
        const float* __restrict__ sl = slut + (t * NNODES + M0 + M1) * 64;
        float P[64];
#pragma unroll
        for (int i = 0; i < 64; ++i) P[i] = sl[i];
        const int* id = idx2 + t * 6;
        int rl = 2 * tid;
        v2f g[6];
#pragma unroll
        for (int j = 0; j < 6; ++j)
            g[j] = *reinterpret_cast<const v2f*>(h1s + id[j] * 128 + rl);
        v2f o = lut_node_v2(P, g[0], g[1], g[2], g[3], g[4], g[5]);
        int row = e * 128 + rl;
        int b = row >> 4, s = row & 15;
        *reinterpret_cast<v2f*>(out + b * (T_TREES * 16) + t * 16 + s) = o;
    }
}

// ===== fallback (ws too small): self-contained single kernel =====
__global__ __launch_bounds__(128) void clut_fb_kernel(
    const float* __restrict__ x,
    const int* __restrict__ idx0, const float* __restrict__ lut0,
    const int* __restrict__ idx1, const float* __restrict__ lut1,
    const int* __restrict__ idx2, const float* __restrict__ lut2,
    float* __restrict__ out) {
    __shared__ __align__(16) float slut[NNODES * 64];
    __shared__ float feat[25 * 128];
    __shared__ float h0[M0 * 128];
    __shared__ float h1[M1 * 128];

    const int tid = threadIdx.x;
    const int t = blockIdx.y;
    for (int i = tid; i < NNODES * 64; i += 128) {
        float v;
        if (i < M0 * 64)              v = lut0[t * (M0 * 64) + i];
        else if (i < (M0 + M1) * 64)  v = lut1[t * (M1 * 64) + (i - M0 * 64)];
        else                          v = lut2[t * 64 + (i - (M0 + M1) * 64)];
        slut[i] = sigmoidf(v);
    }
    const int n = blockIdx.x * 128 + tid;
    const int b = n >> 4, s = n & 15;
    const float* xb = x + b * 64 + (s >> 2) * 8 + (s & 3);
#pragma unroll
    for (int i = 0; i < 5; ++i)
#pragma unroll
        for (int j = 0; j < 5; ++j)
            feat[(i * 5 + j) * 128 + tid] = xb[i * 8 + j];
    __syncthreads();
    for (int m = 0; m < M0; ++m) {
        const int* id = idx0 + (t * M0 + m) * 6;
        v2f g[6];
#pragma unroll
        for (int j = 0; j < 6; ++j) { g[j].x = feat[id[j] * 128 + tid]; g[j].y = 0.f; }
        v2f r = lut_node_v2(slut + m * 64, g[0], g[1], g[2], g[3], g[4], g[5]);
        h0[m * 128 + tid] = r.x;
    }
    for (int m = 0; m < M1; ++m) {
        const int* id = idx1 + (t * M1 + m) * 6;
        v2f g[6];
#pragma unroll
        for (int j = 0; j < 6; ++j) { g[j].x = h0[id[j] * 128 + tid]; g[j].y = 0.f; }
        v2f r = lut_node_v2(slut + (M0 + m) * 64, g[0], g[1], g[2], g[3], g[4], g[5]);
        h1[m * 128 + tid] = r.x;
    }
    {
        const int* id = idx2 + t * 6;
        v2f g[6];
#pragma unroll
        for (int j = 0; j < 6; ++j) { g[j].x = h1[id[j] * 128 + tid]; g[j].y = 0.f; }
        v2f r = lut_node_v2(slut + (M0 + M1) * 64, g[0], g[1], g[2], g[3], g[4], g[5]);
        out[b * (T_TREES * 16) + t * 16 + s] = r.x;
    }
}

extern "C" void kernel_launch(void* const* d_in, const int* in_sizes, int n_in,
                              void* d_out, int out_size, void* d_ws, size_t ws_size,
                              hipStream_t stream) {
    const float* x    = (const float*)d_in[0];
    const int*   idx0 = (const int*)  d_in[1];
    const float* lut0 = (const float*)d_in[2];
    const int*   idx1 = (const int*)  d_in[3];
    const float* lut1 = (const float*)d_in[4];
    const int*   idx2 = (const int*)  d_in[5];
    const float* lut2 = (const float*)d_in[6];
    float* out = (float*)d_out;

    const size_t need = (size_t)(SLUT_ELEMS + T_TREES * M0 * NROWS) * sizeof(float); // 20.3 MB
    if (ws_size >= need) {
        float* slut = (float*)d_ws;
        float* h0   = (float*)d_ws + SLUT_ELEMS;
        sig_kernel<<<SLUT_ELEMS / 4 / 256, 256, 0, stream>>>(lut0, lut1, lut2, slut); // 344 blocks
        l0_kernel<<<dim3((M0 / 4) * T_TREES), 256, 0, stream>>>(x, idx0, slut, h0);   // 1152 blocks
        l12_kernel<<<dim3(8 * T_TREES), 384, 0, stream>>>(h0, idx1, idx2, slut, out); // 1024 blocks
    } else {
        dim3 grid(NROWS / 128, T_TREES);
        clut_fb_kernel<<<grid, 128, 0, stream>>>(x, idx0, lut0, idx1, lut1, idx2, lut2, out);
    }
}